// Round 13
// baseline (326.703 us; speedup 1.0000x reference)
//
#include <hip/hip_runtime.h>
#include <hip/hip_cooperative_groups.h>
#include <math.h>

namespace cg = cooperative_groups;

typedef __attribute__((ext_vector_type(8))) short short8;
typedef __attribute__((ext_vector_type(8))) unsigned short ushort8;
typedef __attribute__((ext_vector_type(4))) float f32x4;
typedef unsigned short ushortT;

#define NB     16
#define CIN    512
#define TT     2048
#define COUT2  1024
#define NSTYLE 128
#define KKTOT  1536      // 3 * 512
#define TPAD   2050      // T + 2 pad rows

#define SCALE_LIN  0.088388347648318447f
#define SCALE_CONV 0.014731391274719736f

__device__ __forceinline__ ushortT f2bf(float f) {
  union { float f; unsigned u; } v; v.f = f;
  unsigned r = v.u + 0x7fffu + ((v.u >> 16) & 1u);
  return (ushortT)(r >> 16);
}

__device__ __forceinline__ void gload16(const void* g, void* l) {
  __builtin_amdgcn_global_load_lds(
      (const __attribute__((address_space(1))) void*)g,
      (__attribute__((address_space(3))) void*)l, 16, 0, 0);
}

// ---------------- conv tile body (R12, verbatim structure) ----------------
#define AFRAG(d, s, f) (*(const short8*)(ldsc + ((d) * 4 + (s)) * 16384 + aoff + (f) * 1024))
#define BFRAG(d, s, g) (*(const short8*)(ldsc + ((d) * 4 + (s)) * 16384 + boff + (g) * 1024))

#define RDA(as_, d, s, mh) do {              \
    as_##0 = AFRAG(d, s, (mh) * 4 + 0);      \
    as_##1 = AFRAG(d, s, (mh) * 4 + 1);      \
    as_##2 = AFRAG(d, s, (mh) * 4 + 2);      \
    as_##3 = AFRAG(d, s, (mh) * 4 + 3);      \
  } while (0)

#define RDB(bs_, d, s) do {                  \
    bs_##0 = BFRAG(d, s, 0);                 \
    bs_##1 = BFRAG(d, s, 1);                 \
    bs_##2 = BFRAG(d, s, 2);                 \
    bs_##3 = BFRAG(d, s, 3);                 \
  } while (0)

#define STAGE_A(d, s, kt) do {                                                   \
    int kc_ = (kt) * 64 + (s) * 32;                                              \
    gload16(wB + (size_t)(co0 + r0) * KKTOT + kc_ + jbs8,                        \
            ldsw + ((d) * 4 + (s)) * 8192 + tid * 8);                            \
    gload16(wB + (size_t)(co0 + r0 + 128) * KKTOT + kc_ + jbs8,                  \
            ldsw + ((d) * 4 + (s)) * 8192 + 4096 + tid * 8);                     \
  } while (0)

#define STAGE_B(d, s, kt) do {                                                   \
    int kc_ = (kt) * 64 + (s) * 32;                                              \
    int tap_ = kc_ >> 9; int ci_ = kc_ & 511;                                    \
    gload16(xB + (size_t)(t0 + r0 + tap_) * CIN + ci_ + jbs8,                    \
            ldsw + ((d) * 4 + 2 + (s)) * 8192 + tid * 8);                        \
    gload16(xB + (size_t)(t0 + r0 + 128 + tap_) * CIN + ci_ + jbs8,              \
            ldsw + ((d) * 4 + 2 + (s)) * 8192 + 4096 + tid * 8);                 \
  } while (0)

#define PHASE(mh, au_, bu_, RD_CODE, STAGES, VMN, BAR) do {                      \
    if (BAR) {                                                                   \
      if ((VMN) == 6)      asm volatile("s_waitcnt vmcnt(6)" ::: "memory");      \
      else if ((VMN) == 4) asm volatile("s_waitcnt vmcnt(4)" ::: "memory");      \
      else if ((VMN) == 0) asm volatile("s_waitcnt vmcnt(0)" ::: "memory");      \
      __builtin_amdgcn_s_barrier();                                              \
    }                                                                            \
    STAGES;                                                                      \
    RD_CODE;                                                                     \
    __builtin_amdgcn_sched_barrier(0);                                           \
    __builtin_amdgcn_s_setprio(1);                                               \
    acc[(mh)*4+0][0] = __builtin_amdgcn_mfma_f32_16x16x32_bf16(au_##0, bu_##0, acc[(mh)*4+0][0], 0, 0, 0); \
    acc[(mh)*4+0][1] = __builtin_amdgcn_mfma_f32_16x16x32_bf16(au_##0, bu_##1, acc[(mh)*4+0][1], 0, 0, 0); \
    acc[(mh)*4+0][2] = __builtin_amdgcn_mfma_f32_16x16x32_bf16(au_##0, bu_##2, acc[(mh)*4+0][2], 0, 0, 0); \
    acc[(mh)*4+0][3] = __builtin_amdgcn_mfma_f32_16x16x32_bf16(au_##0, bu_##3, acc[(mh)*4+0][3], 0, 0, 0); \
    acc[(mh)*4+1][0] = __builtin_amdgcn_mfma_f32_16x16x32_bf16(au_##1, bu_##0, acc[(mh)*4+1][0], 0, 0, 0); \
    acc[(mh)*4+1][1] = __builtin_amdgcn_mfma_f32_16x16x32_bf16(au_##1, bu_##1, acc[(mh)*4+1][1], 0, 0, 0); \
    acc[(mh)*4+1][2] = __builtin_amdgcn_mfma_f32_16x16x32_bf16(au_##1, bu_##2, acc[(mh)*4+1][2], 0, 0, 0); \
    acc[(mh)*4+1][3] = __builtin_amdgcn_mfma_f32_16x16x32_bf16(au_##1, bu_##3, acc[(mh)*4+1][3], 0, 0, 0); \
    acc[(mh)*4+2][0] = __builtin_amdgcn_mfma_f32_16x16x32_bf16(au_##2, bu_##0, acc[(mh)*4+2][0], 0, 0, 0); \
    acc[(mh)*4+2][1] = __builtin_amdgcn_mfma_f32_16x16x32_bf16(au_##2, bu_##1, acc[(mh)*4+2][1], 0, 0, 0); \
    acc[(mh)*4+2][2] = __builtin_amdgcn_mfma_f32_16x16x32_bf16(au_##2, bu_##2, acc[(mh)*4+2][2], 0, 0, 0); \
    acc[(mh)*4+2][3] = __builtin_amdgcn_mfma_f32_16x16x32_bf16(au_##2, bu_##3, acc[(mh)*4+2][3], 0, 0, 0); \
    acc[(mh)*4+3][0] = __builtin_amdgcn_mfma_f32_16x16x32_bf16(au_##3, bu_##0, acc[(mh)*4+3][0], 0, 0, 0); \
    acc[(mh)*4+3][1] = __builtin_amdgcn_mfma_f32_16x16x32_bf16(au_##3, bu_##1, acc[(mh)*4+3][1], 0, 0, 0); \
    acc[(mh)*4+3][2] = __builtin_amdgcn_mfma_f32_16x16x32_bf16(au_##3, bu_##2, acc[(mh)*4+3][2], 0, 0, 0); \
    acc[(mh)*4+3][3] = __builtin_amdgcn_mfma_f32_16x16x32_bf16(au_##3, bu_##3, acc[(mh)*4+3][3], 0, 0, 0); \
    __builtin_amdgcn_s_setprio(0);                                               \
  } while (0)

__device__ __forceinline__ void conv_tile(int wgid, ushortT* ldsw,
                                          const ushortT* __restrict__ wnorm,
                                          const ushortT* __restrict__ xT,
                                          float* __restrict__ out, int tid) {
  const char* ldsc = (const char*)ldsw;
  int b  = wgid >> 5;
  int i5 = wgid & 31;
  int mp = i5 >> 4, r2 = i5 & 15;
  int nt = r2 >> 1, mt = mp * 2 + (r2 & 1);
  int co0 = mt * 256, t0 = nt * 256;

  int l = tid & 63, w = tid >> 6;
  int wm = w & 1, wn = w >> 1;           // 2 x 4 wave grid

  int r0 = tid >> 2;
  int jbs8 = (((tid & 3) ^ ((r0 >> 1) & 3)) << 3);
  int cb = ((l >> 4) ^ ((l >> 1) & 3));
  int aoff = (wm * 128 + (l & 15)) * 64 + cb * 16;
  int boff = 32768 + (wn * 64 + (l & 15)) * 64 + cb * 16;

  const ushortT* wB = wnorm + (size_t)b * COUT2 * KKTOT;
  const ushortT* xB = xT + (size_t)b * TPAD * CIN;

  f32x4 acc[8][4];
#pragma unroll
  for (int i = 0; i < 8; ++i)
#pragma unroll
    for (int j = 0; j < 4; ++j)
      acc[i][j] = (f32x4){0.f, 0.f, 0.f, 0.f};
  short8 ax0 = {}, ax1 = {}, ax2 = {}, ax3 = {};
  short8 ay0 = {}, ay1 = {}, ay2 = {}, ay3 = {};
  short8 bx0 = {}, bx1 = {}, bx2 = {}, bx3 = {};
  short8 by0 = {}, by1 = {}, by2 = {}, by3 = {};

  STAGE_A(0, 0, 0); STAGE_B(0, 0, 0); STAGE_A(0, 1, 0); STAGE_B(0, 1, 0);
  STAGE_B(1, 0, 1); STAGE_A(1, 0, 1); STAGE_B(1, 1, 1);
  asm volatile("s_waitcnt vmcnt(6)" ::: "memory");
  __builtin_amdgcn_s_barrier();
  RDA(ax, 0, 0, 0);
  RDB(bx, 0, 0);

  for (int j = 0; j < 11; ++j) {
    int kt1 = 2 * j + 1;
    int k0n = 2 * j + 2, k1n = 2 * j + 3;
    PHASE(0, ax, bx, { RDA(ay, 0, 0, 1); },                STAGE_A(1, 1, kt1),  6, 1);
    PHASE(1, ay, bx, { RDA(ax, 0, 1, 0); RDB(by, 0, 1); }, STAGE_B(0, 0, k0n), -1, 0);
    PHASE(0, ax, by, { RDA(ay, 0, 1, 1); },                STAGE_A(0, 0, k0n),  6, 1);
    PHASE(1, ay, by, { RDA(ax, 1, 0, 0); RDB(bx, 1, 0); }, STAGE_B(0, 1, k0n), -1, 0);
    PHASE(0, ax, bx, { RDA(ay, 1, 0, 1); },                STAGE_A(0, 1, k0n),  6, 1);
    PHASE(1, ay, bx, { RDA(ax, 1, 1, 0); RDB(by, 1, 1); }, STAGE_B(1, 0, k1n), -1, 0);
    PHASE(0, ax, by, { RDA(ay, 1, 1, 1); },                STAGE_A(1, 0, k1n),  6, 1);
    PHASE(1, ay, by, { RDA(ax, 0, 0, 0); RDB(bx, 0, 0); }, STAGE_B(1, 1, k1n), -1, 0);
  }
  PHASE(0, ax, bx, { RDA(ay, 0, 0, 1); },                STAGE_A(1, 1, 23),  6, 1);
  PHASE(1, ay, bx, { RDA(ax, 0, 1, 0); RDB(by, 0, 1); }, {},                -1, 0);
  PHASE(0, ax, by, { RDA(ay, 0, 1, 1); },                {},                 4, 1);
  PHASE(1, ay, by, { RDA(ax, 1, 0, 0); RDB(bx, 1, 0); }, {},                -1, 0);
  PHASE(0, ax, bx, { RDA(ay, 1, 0, 1); },                {},                 0, 1);
  PHASE(1, ay, bx, { RDA(ax, 1, 1, 0); RDB(by, 1, 1); }, {},                -1, 0);
  PHASE(0, ax, by, { RDA(ay, 1, 1, 1); },                {},                -1, 1);
  PHASE(1, ay, by, { },                                  {},                -1, 0);

#pragma unroll
  for (int f = 0; f < 8; ++f) {
    int cop = co0 + wm * 128 + f * 16 + ((l >> 4) << 2);
    int c = cop >> 1;
    size_t obase = ((size_t)b * (COUT2 / 2) + c) * TT;
#pragma unroll
    for (int g = 0; g < 4; ++g) {
      int t = t0 + wn * 64 + g * 16 + (l & 15);
      f32x4 v = acc[f][g];
      out[obase + t]      = v.x / (1.f + __expf(-v.y));
      out[obase + TT + t] = v.z / (1.f + __expf(-v.w));
    }
  }
}

// ---------------- cooperative mega-kernel ----------------
// 256 blocks x 512 threads, 128 KiB dyn LDS (exactly 1 wg/CU -> co-resident).
// phase1: style (blocks 0-15) + pad-zero + xpose (16 units/block)
// phase2: modw (4 co/block)
// phase3: conv tiles wgid = bid and bid+256 (the former 2 rounds, no dispatch gap)
__global__ __launch_bounds__(512, 1)
void mega(const float* __restrict__ x, const float* __restrict__ c_trg,
          const float* __restrict__ w_s, const float* __restrict__ b_s,
          const float* __restrict__ w_b, const float* __restrict__ b_b,
          const float* __restrict__ weight, float* __restrict__ out,
          float* __restrict__ s, float* __restrict__ beta,
          ushortT* __restrict__ xT, ushortT* __restrict__ wnorm) {
  extern __shared__ ushortT ldsw[];
  int bid = blockIdx.x;
  int tid = threadIdx.x;

  // ---- phase 1a: style + pad-zero (blocks 0-15, all 512 threads) ----
  if (bid < 16) {
    int gid = bid * 512 + tid;        // 0..8191 = b*512 + ci
    int b = gid >> 9, ci = gid & 511;
    const float* ct = c_trg + b * NSTYLE;
    const float* ws = w_s + ci * NSTYLE;
    const float* wb = w_b + ci * NSTYLE;
    float as = 0.f, ab = 0.f;
#pragma unroll 8
    for (int j = 0; j < NSTYLE; ++j) {
      float c = ct[j];
      as += c * ws[j];
      ab += c * wb[j];
    }
    s[gid]    = as * SCALE_LIN + b_s[ci];
    beta[gid] = ab * SCALE_LIN + b_b[ci];
    xT[(size_t)b * TPAD * CIN + ci] = 0;
    xT[((size_t)b * TPAD + TPAD - 1) * CIN + ci] = 0;
  }

  // ---- phase 1b: xpose — 16 units/block, 2 units at a time (half = tid>>8) ----
  {
    float* tf = (float*)ldsw;
    int half = tid >> 8;              // 0 or 1
    int ltid = tid & 255;
    float* myTile = tf + half * (64 * 65);
    int rr = ltid >> 4;               // 0..15
    int c4 = ltid & 15;               // 0..15
    for (int it = 0; it < 8; ++it) {
      int u = bid * 16 + it * 2 + half;      // 0..4095
      int ub = u >> 8, uct = (u >> 5) & 7, utt = u & 31;
      int t0 = utt * 64, ci0 = uct * 64;
      const float* xB = x + (size_t)ub * CIN * TT;
#pragma unroll
      for (int k = 0; k < 4; ++k) {
        int ci = rr + k * 16;
        float4 v = *(const float4*)(xB + (size_t)(ci0 + ci) * TT + t0 + c4 * 4);
        myTile[ci * 65 + c4 * 4 + 0] = v.x; myTile[ci * 65 + c4 * 4 + 1] = v.y;
        myTile[ci * 65 + c4 * 4 + 2] = v.z; myTile[ci * 65 + c4 * 4 + 3] = v.w;
      }
      __syncthreads();
      ushortT* xTB = xT + (size_t)ub * TPAD * CIN;
#pragma unroll
      for (int it2 = 0; it2 < 2; ++it2) {
        int idx = it2 * 256 + ltid;   // 0..511
        int c8 = idx & 7;
        int tl = idx >> 3;
        union { ushort8 v8; ushortT u16[8]; } o;
#pragma unroll
        for (int j = 0; j < 8; ++j) o.u16[j] = f2bf(myTile[(c8 * 8 + j) * 65 + tl]);
        *(ushort8*)(xTB + (size_t)(1 + t0 + tl) * CIN + ci0 + c8 * 8) = o.v8;
      }
      __syncthreads();
    }
  }

  __threadfence();
  cg::this_grid().sync();

  // ---- phase 2: modw — 4 co per block, 2 co at a time across 8 waves ----
  {
    int wv = tid >> 6, l = tid & 63;
    int wv4 = wv & 3;                 // wave-within-co: batches wv4*4..+3
    for (int pass = 0; pass < 2; ++pass) {
      int co = bid * 4 + pass * 2 + (wv >> 2);
      const float* wp = weight + (size_t)co * KKTOT + l * 24;
      float v[24];
#pragma unroll
      for (int j = 0; j < 6; ++j) {
        float4 t = *(const float4*)(wp + j * 4);
        v[j * 4 + 0] = t.x; v[j * 4 + 1] = t.y; v[j * 4 + 2] = t.z; v[j * 4 + 3] = t.w;
      }
      int r = ((co & 511) << 1) | (co >> 9);
#pragma unroll
      for (int bi = 0; bi < 4; ++bi) {
        int b = wv4 * 4 + bi;
        const float* sp = s + b * CIN + l * 8;
        const float* ep = beta + b * CIN + l * 8;
        float4 s0 = *(const float4*)(sp), s1 = *(const float4*)(sp + 4);
        float4 e0 = *(const float4*)(ep), e1 = *(const float4*)(ep + 4);
        float sv[8] = {s0.x, s0.y, s0.z, s0.w, s1.x, s1.y, s1.z, s1.w};
        float ev[8] = {e0.x, e0.y, e0.z, e0.w, e1.x, e1.y, e1.z, e1.w};
        float wm[24];
        float sum = 0.f, sq = 0.f;
#pragma unroll
        for (int c = 0; c < 8; ++c)
#pragma unroll
          for (int k = 0; k < 3; ++k) {
            float val = SCALE_CONV * (v[c * 3 + k] * sv[c] + ev[c]);
            wm[c * 3 + k] = val;
            sum += val; sq += val * val;
          }
#pragma unroll
        for (int off = 32; off; off >>= 1) {
          sum += __shfl_xor(sum, off);
          sq  += __shfl_xor(sq,  off);
        }
        float mean  = sum * (1.0f / 1536.0f);
        float demod = rsqrtf(sq + 1e-8f);
        ushortT* dst = wnorm + ((size_t)b * COUT2 + r) * KKTOT;
#pragma unroll
        for (int k = 0; k < 3; ++k) {
          union { ushort8 v8; ushortT u16[8]; } o;
#pragma unroll
          for (int c = 0; c < 8; ++c) o.u16[c] = f2bf((wm[c * 3 + k] - mean) * demod);
          *(ushort8*)(dst + k * 512 + l * 8) = o.v8;
        }
      }
    }
  }

  __threadfence();
  cg::this_grid().sync();

  // ---- phase 3: conv — former rounds 1 and 2 without a dispatch boundary ----
  {
    int orig = bid;                            // round 1
    int wgid = (orig & 7) * 64 + (orig >> 3);
    conv_tile(wgid, ldsw, wnorm, xT, out, tid);
    __syncthreads();
    orig = bid + 256;                          // round 2
    wgid = (orig & 7) * 64 + (orig >> 3);
    conv_tile(wgid, ldsw, wnorm, xT, out, tid);
  }
}

extern "C" void kernel_launch(void* const* d_in, const int* in_sizes, int n_in,
                              void* d_out, int out_size, void* d_ws, size_t ws_size,
                              hipStream_t stream) {
  const float* x      = (const float*)d_in[0];
  const float* c_trg  = (const float*)d_in[2];
  const float* w_s    = (const float*)d_in[3];
  const float* b_s    = (const float*)d_in[4];
  const float* w_b    = (const float*)d_in[5];
  const float* b_b    = (const float*)d_in[6];
  const float* weight = (const float*)d_in[7];
  float* out = (float*)d_out;

  char* ws = (char*)d_ws;
  float*   s     = (float*)ws;                           // 32 KB
  float*   beta  = (float*)(ws + 32768);                 // 32 KB
  ushortT* xT    = (ushortT*)(ws + 65536);               // 33,587,200 B
  ushortT* wnorm = (ushortT*)(ws + 65536 + 33587200);    // 50,331,648 B

  (void)hipFuncSetAttribute((const void*)mega,
                            hipFuncAttributeMaxDynamicSharedMemorySize, 131072);

  void* args[12] = {(void*)&x, (void*)&c_trg, (void*)&w_s, (void*)&b_s,
                    (void*)&w_b, (void*)&b_b, (void*)&weight, (void*)&out,
                    (void*)&s, (void*)&beta, (void*)&xT, (void*)&wnorm};
  (void)hipLaunchCooperativeKernel((void*)mega, dim3(256), dim3(512),
                                   args, 131072, stream);
}

// Round 14
// 134.968 us; speedup vs baseline: 2.4206x; 2.4206x over previous
//
#include <hip/hip_runtime.h>
#include <math.h>

typedef __attribute__((ext_vector_type(8))) short short8;
typedef __attribute__((ext_vector_type(8))) unsigned short ushort8;
typedef __attribute__((ext_vector_type(4))) float f32x4;
typedef unsigned short ushortT;

#define NB     16
#define CIN    512
#define TT     2048
#define COUT2  1024
#define NSTYLE 128
#define KKTOT  1536      // 3 * 512
#define TPAD   2050      // T + 2 pad rows

#define SCALE_LIN  0.088388347648318447f
#define SCALE_CONV 0.014731391274719736f

__device__ __forceinline__ ushortT f2bf(float f) {
  union { float f; unsigned u; } v; v.f = f;
  unsigned r = v.u + 0x7fffu + ((v.u >> 16) & 1u);
  return (ushortT)(r >> 16);
}

__device__ __forceinline__ void gload16(const void* g, void* l) {
  __builtin_amdgcn_global_load_lds(
      (const __attribute__((address_space(1))) void*)g,
      (__attribute__((address_space(3))) void*)l, 16, 0, 0);
}

// ---------------- s / beta + pad-row zeroing ----------------
__global__ void style_kernel(const float* __restrict__ c_trg,
                             const float* __restrict__ w_s, const float* __restrict__ b_s,
                             const float* __restrict__ w_b, const float* __restrict__ b_b,
                             float* __restrict__ s, float* __restrict__ beta,
                             ushortT* __restrict__ xT) {
  int gid = blockIdx.x * 256 + threadIdx.x;   // 0..8191 = b*512 + ci
  int b = gid >> 9, ci = gid & 511;
  const float* ct = c_trg + b * NSTYLE;
  const float* ws = w_s + ci * NSTYLE;
  const float* wb = w_b + ci * NSTYLE;
  float as = 0.f, ab = 0.f;
#pragma unroll 8
  for (int j = 0; j < NSTYLE; ++j) {
    float c = ct[j];
    as += c * ws[j];
    ab += c * wb[j];
  }
  s[gid]    = as * SCALE_LIN + b_s[ci];
  beta[gid] = ab * SCALE_LIN + b_b[ci];
  xT[(size_t)b * TPAD * CIN + ci] = 0;
  xT[((size_t)b * TPAD + TPAD - 1) * CIN + ci] = 0;
}

// ---------------- fused xpose (blocks 0..4095) + modw (blocks 4096..5119) ----
// xpose and modw are mutually independent (modw needs only style's s/beta);
// fusing lets memory-bound xpose co-schedule with VALU-bound modw.
__global__ void prep_kernel(const float* __restrict__ x, ushortT* __restrict__ xT,
                            const float* __restrict__ weight,
                            const float* __restrict__ s, const float* __restrict__ beta,
                            ushortT* __restrict__ wnorm) {
  int bid = blockIdx.x;
  if (bid < 4096) {
    // ---- xpose unit u = bid : b = u>>8, ct = (u>>5)&7, tt = u&31 ----
    int b = bid >> 8, ct = (bid >> 5) & 7, tt = bid & 31;
    int t0 = tt * 64, ci0 = ct * 64;
    __shared__ float tile[64][65];
    const float* xB = x + (size_t)b * CIN * TT;
    int rr = threadIdx.x >> 4;   // 0..15
    int c4 = threadIdx.x & 15;   // 0..15
#pragma unroll
    for (int it = 0; it < 4; ++it) {
      int ci = rr + it * 16;
      float4 v = *(const float4*)(xB + (size_t)(ci0 + ci) * TT + t0 + c4 * 4);
      tile[ci][c4 * 4 + 0] = v.x; tile[ci][c4 * 4 + 1] = v.y;
      tile[ci][c4 * 4 + 2] = v.z; tile[ci][c4 * 4 + 3] = v.w;
    }
    __syncthreads();
    ushortT* xTB = xT + (size_t)b * TPAD * CIN;
#pragma unroll
    for (int it = 0; it < 2; ++it) {
      int idx = it * 256 + threadIdx.x;   // 0..511
      int c8 = idx & 7;                   // ci chunk (8 bf16)
      int tl = idx >> 3;                  // t within tile (0..63)
      union { ushort8 v8; ushortT u16[8]; } o;
#pragma unroll
      for (int j = 0; j < 8; ++j) o.u16[j] = f2bf(tile[c8 * 8 + j][tl]);
      *(ushort8*)(xTB + (size_t)(1 + t0 + tl) * CIN + ci0 + c8 * 8) = o.v8;
    }
  } else {
    // ---- modw co = bid - 4096; wave wv handles batches 4wv..4wv+3 ----
    int co = bid - 4096;
    int wv = threadIdx.x >> 6;
    int l  = threadIdx.x & 63;
    const float* wp = weight + (size_t)co * KKTOT + l * 24;
    float v[24];
#pragma unroll
    for (int j = 0; j < 6; ++j) {
      float4 t = *(const float4*)(wp + j * 4);
      v[j * 4 + 0] = t.x; v[j * 4 + 1] = t.y; v[j * 4 + 2] = t.z; v[j * 4 + 3] = t.w;
    }
    int r = ((co & 511) << 1) | (co >> 9);     // GLU-interleaved row
#pragma unroll
    for (int bi = 0; bi < 4; ++bi) {
      int b = wv * 4 + bi;
      const float* sp = s + b * CIN + l * 8;
      const float* ep = beta + b * CIN + l * 8;
      float4 s0 = *(const float4*)(sp), s1 = *(const float4*)(sp + 4);
      float4 e0 = *(const float4*)(ep), e1 = *(const float4*)(ep + 4);
      float sv[8] = {s0.x, s0.y, s0.z, s0.w, s1.x, s1.y, s1.z, s1.w};
      float ev[8] = {e0.x, e0.y, e0.z, e0.w, e1.x, e1.y, e1.z, e1.w};
      float wm[24];
      float sum = 0.f, sq = 0.f;
#pragma unroll
      for (int c = 0; c < 8; ++c)
#pragma unroll
        for (int k = 0; k < 3; ++k) {
          float val = SCALE_CONV * (v[c * 3 + k] * sv[c] + ev[c]);
          wm[c * 3 + k] = val;
          sum += val; sq += val * val;
        }
#pragma unroll
      for (int off = 32; off; off >>= 1) {
        sum += __shfl_xor(sum, off);
        sq  += __shfl_xor(sq,  off);
      }
      float mean  = sum * (1.0f / 1536.0f);
      float demod = rsqrtf(sq + 1e-8f);
      ushortT* dst = wnorm + ((size_t)b * COUT2 + r) * KKTOT;
#pragma unroll
      for (int k = 0; k < 3; ++k) {
        union { ushort8 v8; ushortT u16[8]; } o;
#pragma unroll
        for (int c = 0; c < 8; ++c) o.u16[c] = f2bf((wm[c * 3 + k] - mean) * demod);
        *(ushort8*)(dst + k * 512 + l * 8) = o.v8;
      }
    }
  }
}

// ---------------- main conv-as-GEMM: 256^2 tile, 4-barrier read-ahead (R12) ----
// LDS regions: ridx = ((dbuf*2 + op)*2 + ks), region [256][32] bf16 = 16384 B.
// Rows 64B = 4x16B blocks XOR-swizzled by (row>>1)&3. 8 regions = 128 KiB.

#define AFRAG(d, s, f) (*(const short8*)(ldsc + ((d) * 4 + (s)) * 16384 + aoff + (f) * 1024))
#define BFRAG(d, s, g) (*(const short8*)(ldsc + ((d) * 4 + (s)) * 16384 + boff + (g) * 1024))

#define RDA(as_, d, s, mh) do {              \
    as_##0 = AFRAG(d, s, (mh) * 4 + 0);      \
    as_##1 = AFRAG(d, s, (mh) * 4 + 1);      \
    as_##2 = AFRAG(d, s, (mh) * 4 + 2);      \
    as_##3 = AFRAG(d, s, (mh) * 4 + 3);      \
  } while (0)

#define RDB(bs_, d, s) do {                  \
    bs_##0 = BFRAG(d, s, 0);                 \
    bs_##1 = BFRAG(d, s, 1);                 \
    bs_##2 = BFRAG(d, s, 2);                 \
    bs_##3 = BFRAG(d, s, 3);                 \
  } while (0)

#define STAGE_A(d, s, kt) do {                                                   \
    int kc_ = (kt) * 64 + (s) * 32;                                              \
    gload16(wB + (size_t)(co0 + r0) * KKTOT + kc_ + jbs8,                        \
            ldsw + ((d) * 4 + (s)) * 8192 + tid * 8);                            \
    gload16(wB + (size_t)(co0 + r0 + 128) * KKTOT + kc_ + jbs8,                  \
            ldsw + ((d) * 4 + (s)) * 8192 + 4096 + tid * 8);                     \
  } while (0)

#define STAGE_B(d, s, kt) do {                                                   \
    int kc_ = (kt) * 64 + (s) * 32;                                              \
    int tap_ = kc_ >> 9; int ci_ = kc_ & 511;                                    \
    gload16(xB + (size_t)(t0 + r0 + tap_) * CIN + ci_ + jbs8,                    \
            ldsw + ((d) * 4 + 2 + (s)) * 8192 + tid * 8);                        \
    gload16(xB + (size_t)(t0 + r0 + 128 + tap_) * CIN + ci_ + jbs8,              \
            ldsw + ((d) * 4 + 2 + (s)) * 8192 + 4096 + tid * 8);                 \
  } while (0)

// BAR=1: [vmcnt(VMN) if >=0; s_barrier] at top. BAR=0: no sync at top.
#define PHASE(mh, au_, bu_, RD_CODE, STAGES, VMN, BAR) do {                      \
    if (BAR) {                                                                   \
      if ((VMN) == 6)      asm volatile("s_waitcnt vmcnt(6)" ::: "memory");      \
      else if ((VMN) == 4) asm volatile("s_waitcnt vmcnt(4)" ::: "memory");      \
      else if ((VMN) == 0) asm volatile("s_waitcnt vmcnt(0)" ::: "memory");      \
      __builtin_amdgcn_s_barrier();                                              \
    }                                                                            \
    STAGES;                                                                      \
    RD_CODE;                                                                     \
    __builtin_amdgcn_sched_barrier(0);  /* pin reads ABOVE the MFMA cluster */   \
    __builtin_amdgcn_s_setprio(1);                                               \
    acc[(mh)*4+0][0] = __builtin_amdgcn_mfma_f32_16x16x32_bf16(au_##0, bu_##0, acc[(mh)*4+0][0], 0, 0, 0); \
    acc[(mh)*4+0][1] = __builtin_amdgcn_mfma_f32_16x16x32_bf16(au_##0, bu_##1, acc[(mh)*4+0][1], 0, 0, 0); \
    acc[(mh)*4+0][2] = __builtin_amdgcn_mfma_f32_16x16x32_bf16(au_##0, bu_##2, acc[(mh)*4+0][2], 0, 0, 0); \
    acc[(mh)*4+0][3] = __builtin_amdgcn_mfma_f32_16x16x32_bf16(au_##0, bu_##3, acc[(mh)*4+0][3], 0, 0, 0); \
    acc[(mh)*4+1][0] = __builtin_amdgcn_mfma_f32_16x16x32_bf16(au_##1, bu_##0, acc[(mh)*4+1][0], 0, 0, 0); \
    acc[(mh)*4+1][1] = __builtin_amdgcn_mfma_f32_16x16x32_bf16(au_##1, bu_##1, acc[(mh)*4+1][1], 0, 0, 0); \
    acc[(mh)*4+1][2] = __builtin_amdgcn_mfma_f32_16x16x32_bf16(au_##1, bu_##2, acc[(mh)*4+1][2], 0, 0, 0); \
    acc[(mh)*4+1][3] = __builtin_amdgcn_mfma_f32_16x16x32_bf16(au_##1, bu_##3, acc[(mh)*4+1][3], 0, 0, 0); \
    acc[(mh)*4+2][0] = __builtin_amdgcn_mfma_f32_16x16x32_bf16(au_##2, bu_##0, acc[(mh)*4+2][0], 0, 0, 0); \
    acc[(mh)*4+2][1] = __builtin_amdgcn_mfma_f32_16x16x32_bf16(au_##2, bu_##1, acc[(mh)*4+2][1], 0, 0, 0); \
    acc[(mh)*4+2][2] = __builtin_amdgcn_mfma_f32_16x16x32_bf16(au_##2, bu_##2, acc[(mh)*4+2][2], 0, 0, 0); \
    acc[(mh)*4+2][3] = __builtin_amdgcn_mfma_f32_16x16x32_bf16(au_##2, bu_##3, acc[(mh)*4+2][3], 0, 0, 0); \
    acc[(mh)*4+3][0] = __builtin_amdgcn_mfma_f32_16x16x32_bf16(au_##3, bu_##0, acc[(mh)*4+3][0], 0, 0, 0); \
    acc[(mh)*4+3][1] = __builtin_amdgcn_mfma_f32_16x16x32_bf16(au_##3, bu_##1, acc[(mh)*4+3][1], 0, 0, 0); \
    acc[(mh)*4+3][2] = __builtin_amdgcn_mfma_f32_16x16x32_bf16(au_##3, bu_##2, acc[(mh)*4+3][2], 0, 0, 0); \
    acc[(mh)*4+3][3] = __builtin_amdgcn_mfma_f32_16x16x32_bf16(au_##3, bu_##3, acc[(mh)*4+3][3], 0, 0, 0); \
    __builtin_amdgcn_s_setprio(0);                                               \
  } while (0)

__global__ __launch_bounds__(512, 2)
void conv_gemm8(const ushortT* __restrict__ wnorm, const ushortT* __restrict__ xT,
                float* __restrict__ out) {
  extern __shared__ ushortT ldsw[];
  const char* ldsc = (const char*)ldsw;

  // XCD-chunked bijective swizzle (512 blocks % 8 == 0)
  int orig = blockIdx.x;
  int wgid = (orig & 7) * 64 + (orig >> 3);
  int b  = wgid >> 5;
  int i5 = wgid & 31;
  int mp = i5 >> 4, r2 = i5 & 15;
  int nt = r2 >> 1, mt = mp * 2 + (r2 & 1);
  int co0 = mt * 256, t0 = nt * 256;

  int tid = threadIdx.x;
  int l = tid & 63, w = tid >> 6;
  int wm = w & 1, wn = w >> 1;           // 2 x 4 wave grid

  int r0 = tid >> 2;
  int jbs8 = (((tid & 3) ^ ((r0 >> 1) & 3)) << 3);
  int cb = ((l >> 4) ^ ((l >> 1) & 3));
  int aoff = (wm * 128 + (l & 15)) * 64 + cb * 16;
  int boff = 32768 + (wn * 64 + (l & 15)) * 64 + cb * 16;  // B regions at +2 ridx

  const ushortT* wB = wnorm + (size_t)b * COUT2 * KKTOT;
  const ushortT* xB = xT + (size_t)b * TPAD * CIN;

  f32x4 acc[8][4];
#pragma unroll
  for (int i = 0; i < 8; ++i)
#pragma unroll
    for (int j = 0; j < 4; ++j)
      acc[i][j] = (f32x4){0.f, 0.f, 0.f, 0.f};
  short8 ax0 = {}, ax1 = {}, ax2 = {}, ax3 = {};
  short8 ay0 = {}, ay1 = {}, ay2 = {}, ay3 = {};
  short8 bx0 = {}, bx1 = {}, bx2 = {}, bx3 = {};
  short8 by0 = {}, by1 = {}, by2 = {}, by3 = {};

  // prologue: kt0 all 4 halves, then kt1 {B-ks0, A-ks0, B-ks1}; then frags(win1)
  STAGE_A(0, 0, 0); STAGE_B(0, 0, 0); STAGE_A(0, 1, 0); STAGE_B(0, 1, 0);
  STAGE_B(1, 0, 1); STAGE_A(1, 0, 1); STAGE_B(1, 1, 1);
  asm volatile("s_waitcnt vmcnt(6)" ::: "memory");
  __builtin_amdgcn_s_barrier();
  RDA(ax, 0, 0, 0);
  RDB(bx, 0, 0);

  for (int j = 0; j < 11; ++j) {
    int kt1 = 2 * j + 1;
    int k0n = 2 * j + 2, k1n = 2 * j + 3;
    PHASE(0, ax, bx, { RDA(ay, 0, 0, 1); },                STAGE_A(1, 1, kt1),  6, 1);
    PHASE(1, ay, bx, { RDA(ax, 0, 1, 0); RDB(by, 0, 1); }, STAGE_B(0, 0, k0n), -1, 0);
    PHASE(0, ax, by, { RDA(ay, 0, 1, 1); },                STAGE_A(0, 0, k0n),  6, 1);
    PHASE(1, ay, by, { RDA(ax, 1, 0, 0); RDB(bx, 1, 0); }, STAGE_B(0, 1, k0n), -1, 0);
    PHASE(0, ax, bx, { RDA(ay, 1, 0, 1); },                STAGE_A(0, 1, k0n),  6, 1);
    PHASE(1, ay, bx, { RDA(ax, 1, 1, 0); RDB(by, 1, 1); }, STAGE_B(1, 0, k1n), -1, 0);
    PHASE(0, ax, by, { RDA(ay, 1, 1, 1); },                STAGE_A(1, 0, k1n),  6, 1);
    PHASE(1, ay, by, { RDA(ax, 0, 0, 0); RDB(bx, 0, 0); }, STAGE_B(1, 1, k1n), -1, 0);
  }
  // peeled final iteration (kt0=22 in dbuf0, kt1=23 in dbuf1)
  PHASE(0, ax, bx, { RDA(ay, 0, 0, 1); },                STAGE_A(1, 1, 23),  6, 1);
  PHASE(1, ay, bx, { RDA(ax, 0, 1, 0); RDB(by, 0, 1); }, {},                -1, 0);
  PHASE(0, ax, by, { RDA(ay, 0, 1, 1); },                {},                 4, 1);
  PHASE(1, ay, by, { RDA(ax, 1, 0, 0); RDB(bx, 1, 0); }, {},                -1, 0);
  PHASE(0, ax, bx, { RDA(ay, 1, 0, 1); },                {},                 0, 1);
  PHASE(1, ay, bx, { RDA(ax, 1, 1, 0); RDB(by, 1, 1); }, {},                -1, 0);
  PHASE(0, ax, by, { RDA(ay, 1, 1, 1); },                {},                -1, 1);
  PHASE(1, ay, by, { },                                  {},                -1, 0);

  // epilogue: rows are GLU-interleaved co'; regs (x,y)/(z,w) = (a,g) channel pairs
#pragma unroll
  for (int f = 0; f < 8; ++f) {
    int cop = co0 + wm * 128 + f * 16 + ((l >> 4) << 2);
    int c = cop >> 1;
    size_t obase = ((size_t)b * (COUT2 / 2) + c) * TT;
#pragma unroll
    for (int g = 0; g < 4; ++g) {
      int t = t0 + wn * 64 + g * 16 + (l & 15);
      f32x4 v = acc[f][g];
      out[obase + t]      = v.x / (1.f + __expf(-v.y));
      out[obase + TT + t] = v.z / (1.f + __expf(-v.w));
    }
  }
}

extern "C" void kernel_launch(void* const* d_in, const int* in_sizes, int n_in,
                              void* d_out, int out_size, void* d_ws, size_t ws_size,
                              hipStream_t stream) {
  const float* x      = (const float*)d_in[0];
  const float* c_trg  = (const float*)d_in[2];
  const float* w_s    = (const float*)d_in[3];
  const float* b_s    = (const float*)d_in[4];
  const float* w_b    = (const float*)d_in[5];
  const float* b_b    = (const float*)d_in[6];
  const float* weight = (const float*)d_in[7];
  float* out = (float*)d_out;

  char* ws = (char*)d_ws;
  float*   s     = (float*)ws;                           // 32 KB
  float*   beta  = (float*)(ws + 32768);                 // 32 KB
  ushortT* xT    = (ushortT*)(ws + 65536);               // 33,587,200 B
  ushortT* wnorm = (ushortT*)(ws + 65536 + 33587200);    // 50,331,648 B

  (void)hipFuncSetAttribute((const void*)conv_gemm8,
                            hipFuncAttributeMaxDynamicSharedMemorySize, 131072);

  style_kernel<<<32, 256, 0, stream>>>(c_trg, w_s, b_s, w_b, b_b, s, beta, xT);
  prep_kernel<<<5120, 256, 0, stream>>>(x, xT, weight, s, beta, wnorm);
  conv_gemm8<<<512, 512, 131072, stream>>>(wnorm, xT, out);
}

// Round 15
// 132.469 us; speedup vs baseline: 2.4663x; 1.0189x over previous
//
#include <hip/hip_runtime.h>
#include <math.h>

typedef __attribute__((ext_vector_type(8))) short short8;
typedef __attribute__((ext_vector_type(8))) unsigned short ushort8;
typedef __attribute__((ext_vector_type(4))) float f32x4;
typedef unsigned short ushortT;

#define NB     16
#define CIN    512
#define TT     2048
#define COUT2  1024
#define NSTYLE 128
#define KKTOT  1536      // 3 * 512
#define TPAD   2050      // T + 2 pad rows

#define SCALE_LIN  0.088388347648318447f
#define SCALE_CONV 0.014731391274719736f

__device__ __forceinline__ ushortT f2bf(float f) {
  union { float f; unsigned u; } v; v.f = f;
  unsigned r = v.u + 0x7fffu + ((v.u >> 16) & 1u);
  return (ushortT)(r >> 16);
}

__device__ __forceinline__ void gload16(const void* g, void* l) {
  __builtin_amdgcn_global_load_lds(
      (const __attribute__((address_space(1))) void*)g,
      (__attribute__((address_space(3))) void*)l, 16, 0, 0);
}

// ---------------- s / beta + pad-row zeroing ----------------
__global__ void style_kernel(const float* __restrict__ c_trg,
                             const float* __restrict__ w_s, const float* __restrict__ b_s,
                             const float* __restrict__ w_b, const float* __restrict__ b_b,
                             float* __restrict__ s, float* __restrict__ beta,
                             ushortT* __restrict__ xT) {
  int gid = blockIdx.x * 256 + threadIdx.x;   // 0..8191 = b*512 + ci
  int b = gid >> 9, ci = gid & 511;
  const float* ct = c_trg + b * NSTYLE;
  const float* ws = w_s + ci * NSTYLE;
  const float* wb = w_b + ci * NSTYLE;
  float as = 0.f, ab = 0.f;
#pragma unroll 8
  for (int j = 0; j < NSTYLE; ++j) {
    float c = ct[j];
    as += c * ws[j];
    ab += c * wb[j];
  }
  s[gid]    = as * SCALE_LIN + b_s[ci];
  beta[gid] = ab * SCALE_LIN + b_b[ci];
  xT[(size_t)b * TPAD * CIN + ci] = 0;
  xT[((size_t)b * TPAD + TPAD - 1) * CIN + ci] = 0;
}

// ---------------- x [b][ci][t] f32 -> xT [b][t+1][ci] bf16 ----------------
// 512 blocks x 256 threads; block = (b, ci-tile, t-group), 8 t-tile units looped.
__global__ void xpose_kernel(const float* __restrict__ x, ushortT* __restrict__ xT) {
  int bid = blockIdx.x;                // b = bid>>5, ct = (bid>>2)&7, tg = bid&3
  int b  = bid >> 5;
  int ci0 = ((bid >> 2) & 7) * 64;
  int tg  = bid & 3;
  __shared__ float tile[64][65];
  const float* xB = x + (size_t)b * CIN * TT;
  ushortT* xTB = xT + (size_t)b * TPAD * CIN;
  int rr = threadIdx.x >> 4;   // 0..15
  int c4 = threadIdx.x & 15;   // 0..15
  for (int it = 0; it < 8; ++it) {
    int t0 = (tg * 8 + it) * 64;
#pragma unroll
    for (int k = 0; k < 4; ++k) {
      int ci = rr + k * 16;
      float4 v = *(const float4*)(xB + (size_t)(ci0 + ci) * TT + t0 + c4 * 4);
      tile[ci][c4 * 4 + 0] = v.x; tile[ci][c4 * 4 + 1] = v.y;
      tile[ci][c4 * 4 + 2] = v.z; tile[ci][c4 * 4 + 3] = v.w;
    }
    __syncthreads();
#pragma unroll
    for (int it2 = 0; it2 < 2; ++it2) {
      int idx = it2 * 256 + threadIdx.x;   // 0..511
      int c8 = idx & 7;                    // ci chunk (8 bf16)
      int tl = idx >> 3;                   // t within tile (0..63)
      union { ushort8 v8; ushortT u16[8]; } o;
#pragma unroll
      for (int j = 0; j < 8; ++j) o.u16[j] = f2bf(tile[c8 * 8 + j][tl]);
      *(ushort8*)(xTB + (size_t)(1 + t0 + tl) * CIN + ci0 + c8 * 8) = o.v8;
    }
    __syncthreads();   // WAR: tile reused next unit
  }
}

// ---------------- modulate + demod-normalize weights -> bf16 ----------------
// Wave-per-batch: lane l owns ci in [8l, 8l+8) (24 contiguous weight floats).
__global__ void modw_kernel(const float* __restrict__ weight,
                            const float* __restrict__ s, const float* __restrict__ beta,
                            ushortT* __restrict__ wnorm) {
  int co = blockIdx.x;
  int wv = threadIdx.x >> 6;
  int l  = threadIdx.x & 63;
  const float* wp = weight + (size_t)co * KKTOT + l * 24;
  float v[24];
#pragma unroll
  for (int j = 0; j < 6; ++j) {
    float4 t = *(const float4*)(wp + j * 4);
    v[j * 4 + 0] = t.x; v[j * 4 + 1] = t.y; v[j * 4 + 2] = t.z; v[j * 4 + 3] = t.w;
  }
  int r = ((co & 511) << 1) | (co >> 9);     // GLU-interleaved row
#pragma unroll
  for (int bi = 0; bi < 4; ++bi) {
    int b = wv * 4 + bi;
    const float* sp = s + b * CIN + l * 8;
    const float* ep = beta + b * CIN + l * 8;
    float4 s0 = *(const float4*)(sp), s1 = *(const float4*)(sp + 4);
    float4 e0 = *(const float4*)(ep), e1 = *(const float4*)(ep + 4);
    float sv[8] = {s0.x, s0.y, s0.z, s0.w, s1.x, s1.y, s1.z, s1.w};
    float ev[8] = {e0.x, e0.y, e0.z, e0.w, e1.x, e1.y, e1.z, e1.w};
    float wm[24];
    float sum = 0.f, sq = 0.f;
#pragma unroll
    for (int c = 0; c < 8; ++c)
#pragma unroll
      for (int k = 0; k < 3; ++k) {
        float val = SCALE_CONV * (v[c * 3 + k] * sv[c] + ev[c]);
        wm[c * 3 + k] = val;
        sum += val; sq += val * val;
      }
#pragma unroll
    for (int off = 32; off; off >>= 1) {
      sum += __shfl_xor(sum, off);
      sq  += __shfl_xor(sq,  off);
    }
    float mean  = sum * (1.0f / 1536.0f);
    float demod = rsqrtf(sq + 1e-8f);
    ushortT* dst = wnorm + ((size_t)b * COUT2 + r) * KKTOT;
#pragma unroll
    for (int k = 0; k < 3; ++k) {
      union { ushort8 v8; ushortT u16[8]; } o;
#pragma unroll
      for (int c = 0; c < 8; ++c) o.u16[c] = f2bf((wm[c * 3 + k] - mean) * demod);
      *(ushort8*)(dst + k * 512 + l * 8) = o.v8;
    }
  }
}

// ---------------- main conv-as-GEMM: 256^2 tile, 4-barrier read-ahead (R12) ----
// LDS regions: ridx = ((dbuf*2 + op)*2 + ks), region [256][32] bf16 = 16384 B.
// Rows 64B = 4x16B blocks XOR-swizzled by (row>>1)&3. 8 regions = 128 KiB.

#define AFRAG(d, s, f) (*(const short8*)(ldsc + ((d) * 4 + (s)) * 16384 + aoff + (f) * 1024))
#define BFRAG(d, s, g) (*(const short8*)(ldsc + ((d) * 4 + (s)) * 16384 + boff + (g) * 1024))

#define RDA(as_, d, s, mh) do {              \
    as_##0 = AFRAG(d, s, (mh) * 4 + 0);      \
    as_##1 = AFRAG(d, s, (mh) * 4 + 1);      \
    as_##2 = AFRAG(d, s, (mh) * 4 + 2);      \
    as_##3 = AFRAG(d, s, (mh) * 4 + 3);      \
  } while (0)

#define RDB(bs_, d, s) do {                  \
    bs_##0 = BFRAG(d, s, 0);                 \
    bs_##1 = BFRAG(d, s, 1);                 \
    bs_##2 = BFRAG(d, s, 2);                 \
    bs_##3 = BFRAG(d, s, 3);                 \
  } while (0)

#define STAGE_A(d, s, kt) do {                                                   \
    int kc_ = (kt) * 64 + (s) * 32;                                              \
    gload16(wB + (size_t)(co0 + r0) * KKTOT + kc_ + jbs8,                        \
            ldsw + ((d) * 4 + (s)) * 8192 + tid * 8);                            \
    gload16(wB + (size_t)(co0 + r0 + 128) * KKTOT + kc_ + jbs8,                  \
            ldsw + ((d) * 4 + (s)) * 8192 + 4096 + tid * 8);                     \
  } while (0)

#define STAGE_B(d, s, kt) do {                                                   \
    int kc_ = (kt) * 64 + (s) * 32;                                              \
    int tap_ = kc_ >> 9; int ci_ = kc_ & 511;                                    \
    gload16(xB + (size_t)(t0 + r0 + tap_) * CIN + ci_ + jbs8,                    \
            ldsw + ((d) * 4 + 2 + (s)) * 8192 + tid * 8);                        \
    gload16(xB + (size_t)(t0 + r0 + 128 + tap_) * CIN + ci_ + jbs8,              \
            ldsw + ((d) * 4 + 2 + (s)) * 8192 + 4096 + tid * 8);                 \
  } while (0)

// BAR=1: [vmcnt(VMN) if >=0; s_barrier] at top. BAR=0: no sync at top.
#define PHASE(mh, au_, bu_, RD_CODE, STAGES, VMN, BAR) do {                      \
    if (BAR) {                                                                   \
      if ((VMN) == 6)      asm volatile("s_waitcnt vmcnt(6)" ::: "memory");      \
      else if ((VMN) == 4) asm volatile("s_waitcnt vmcnt(4)" ::: "memory");      \
      else if ((VMN) == 0) asm volatile("s_waitcnt vmcnt(0)" ::: "memory");      \
      __builtin_amdgcn_s_barrier();                                              \
    }                                                                            \
    STAGES;                                                                      \
    RD_CODE;                                                                     \
    __builtin_amdgcn_sched_barrier(0);  /* pin reads ABOVE the MFMA cluster */   \
    __builtin_amdgcn_s_setprio(1);                                               \
    acc[(mh)*4+0][0] = __builtin_amdgcn_mfma_f32_16x16x32_bf16(au_##0, bu_##0, acc[(mh)*4+0][0], 0, 0, 0); \
    acc[(mh)*4+0][1] = __builtin_amdgcn_mfma_f32_16x16x32_bf16(au_##0, bu_##1, acc[(mh)*4+0][1], 0, 0, 0); \
    acc[(mh)*4+0][2] = __builtin_amdgcn_mfma_f32_16x16x32_bf16(au_##0, bu_##2, acc[(mh)*4+0][2], 0, 0, 0); \
    acc[(mh)*4+0][3] = __builtin_amdgcn_mfma_f32_16x16x32_bf16(au_##0, bu_##3, acc[(mh)*4+0][3], 0, 0, 0); \
    acc[(mh)*4+1][0] = __builtin_amdgcn_mfma_f32_16x16x32_bf16(au_##1, bu_##0, acc[(mh)*4+1][0], 0, 0, 0); \
    acc[(mh)*4+1][1] = __builtin_amdgcn_mfma_f32_16x16x32_bf16(au_##1, bu_##1, acc[(mh)*4+1][1], 0, 0, 0); \
    acc[(mh)*4+1][2] = __builtin_amdgcn_mfma_f32_16x16x32_bf16(au_##1, bu_##2, acc[(mh)*4+1][2], 0, 0, 0); \
    acc[(mh)*4+1][3] = __builtin_amdgcn_mfma_f32_16x16x32_bf16(au_##1, bu_##3, acc[(mh)*4+1][3], 0, 0, 0); \
    acc[(mh)*4+2][0] = __builtin_amdgcn_mfma_f32_16x16x32_bf16(au_##2, bu_##0, acc[(mh)*4+2][0], 0, 0, 0); \
    acc[(mh)*4+2][1] = __builtin_amdgcn_mfma_f32_16x16x32_bf16(au_##2, bu_##1, acc[(mh)*4+2][1], 0, 0, 0); \
    acc[(mh)*4+2][2] = __builtin_amdgcn_mfma_f32_16x16x32_bf16(au_##2, bu_##2, acc[(mh)*4+2][2], 0, 0, 0); \
    acc[(mh)*4+2][3] = __builtin_amdgcn_mfma_f32_16x16x32_bf16(au_##2, bu_##3, acc[(mh)*4+2][3], 0, 0, 0); \
    acc[(mh)*4+3][0] = __builtin_amdgcn_mfma_f32_16x16x32_bf16(au_##3, bu_##0, acc[(mh)*4+3][0], 0, 0, 0); \
    acc[(mh)*4+3][1] = __builtin_amdgcn_mfma_f32_16x16x32_bf16(au_##3, bu_##1, acc[(mh)*4+3][1], 0, 0, 0); \
    acc[(mh)*4+3][2] = __builtin_amdgcn_mfma_f32_16x16x32_bf16(au_##3, bu_##2, acc[(mh)*4+3][2], 0, 0, 0); \
    acc[(mh)*4+3][3] = __builtin_amdgcn_mfma_f32_16x16x32_bf16(au_##3, bu_##3, acc[(mh)*4+3][3], 0, 0, 0); \
    __builtin_amdgcn_s_setprio(0);                                               \
  } while (0)

__global__ __launch_bounds__(512, 2)
void conv_gemm8(const ushortT* __restrict__ wnorm, const ushortT* __restrict__ xT,
                float* __restrict__ out) {
  extern __shared__ ushortT ldsw[];
  const char* ldsc = (const char*)ldsw;

  // XCD-chunked bijective swizzle (512 blocks % 8 == 0)
  int orig = blockIdx.x;
  int wgid = (orig & 7) * 64 + (orig >> 3);
  int b  = wgid >> 5;
  int i5 = wgid & 31;
  int mp = i5 >> 4, r2 = i5 & 15;
  int nt = r2 >> 1, mt = mp * 2 + (r2 & 1);
  int co0 = mt * 256, t0 = nt * 256;

  int tid = threadIdx.x;
  int l = tid & 63, w = tid >> 6;
  int wm = w & 1, wn = w >> 1;           // 2 x 4 wave grid

  int r0 = tid >> 2;
  int jbs8 = (((tid & 3) ^ ((r0 >> 1) & 3)) << 3);
  int cb = ((l >> 4) ^ ((l >> 1) & 3));
  int aoff = (wm * 128 + (l & 15)) * 64 + cb * 16;
  int boff = 32768 + (wn * 64 + (l & 15)) * 64 + cb * 16;  // B regions at +2 ridx

  const ushortT* wB = wnorm + (size_t)b * COUT2 * KKTOT;
  const ushortT* xB = xT + (size_t)b * TPAD * CIN;

  f32x4 acc[8][4];
#pragma unroll
  for (int i = 0; i < 8; ++i)
#pragma unroll
    for (int j = 0; j < 4; ++j)
      acc[i][j] = (f32x4){0.f, 0.f, 0.f, 0.f};
  short8 ax0 = {}, ax1 = {}, ax2 = {}, ax3 = {};
  short8 ay0 = {}, ay1 = {}, ay2 = {}, ay3 = {};
  short8 bx0 = {}, bx1 = {}, bx2 = {}, bx3 = {};
  short8 by0 = {}, by1 = {}, by2 = {}, by3 = {};

  // prologue: kt0 all 4 halves, then kt1 {B-ks0, A-ks0, B-ks1}; then frags(win1)
  STAGE_A(0, 0, 0); STAGE_B(0, 0, 0); STAGE_A(0, 1, 0); STAGE_B(0, 1, 0);
  STAGE_B(1, 0, 1); STAGE_A(1, 0, 1); STAGE_B(1, 1, 1);
  asm volatile("s_waitcnt vmcnt(6)" ::: "memory");
  __builtin_amdgcn_s_barrier();
  RDA(ax, 0, 0, 0);
  RDB(bx, 0, 0);

  for (int j = 0; j < 11; ++j) {
    int kt1 = 2 * j + 1;
    int k0n = 2 * j + 2, k1n = 2 * j + 3;
    PHASE(0, ax, bx, { RDA(ay, 0, 0, 1); },                STAGE_A(1, 1, kt1),  6, 1);
    PHASE(1, ay, bx, { RDA(ax, 0, 1, 0); RDB(by, 0, 1); }, STAGE_B(0, 0, k0n), -1, 0);
    PHASE(0, ax, by, { RDA(ay, 0, 1, 1); },                STAGE_A(0, 0, k0n),  6, 1);
    PHASE(1, ay, by, { RDA(ax, 1, 0, 0); RDB(bx, 1, 0); }, STAGE_B(0, 1, k0n), -1, 0);
    PHASE(0, ax, bx, { RDA(ay, 1, 0, 1); },                STAGE_A(0, 1, k0n),  6, 1);
    PHASE(1, ay, bx, { RDA(ax, 1, 1, 0); RDB(by, 1, 1); }, STAGE_B(1, 0, k1n), -1, 0);
    PHASE(0, ax, by, { RDA(ay, 1, 1, 1); },                STAGE_A(1, 0, k1n),  6, 1);
    PHASE(1, ay, by, { RDA(ax, 0, 0, 0); RDB(bx, 0, 0); }, STAGE_B(1, 1, k1n), -1, 0);
  }
  // peeled final iteration (kt0=22 in dbuf0, kt1=23 in dbuf1)
  PHASE(0, ax, bx, { RDA(ay, 0, 0, 1); },                STAGE_A(1, 1, 23),  6, 1);
  PHASE(1, ay, bx, { RDA(ax, 0, 1, 0); RDB(by, 0, 1); }, {},                -1, 0);
  PHASE(0, ax, by, { RDA(ay, 0, 1, 1); },                {},                 4, 1);
  PHASE(1, ay, by, { RDA(ax, 1, 0, 0); RDB(bx, 1, 0); }, {},                -1, 0);
  PHASE(0, ax, bx, { RDA(ay, 1, 0, 1); },                {},                 0, 1);
  PHASE(1, ay, bx, { RDA(ax, 1, 1, 0); RDB(by, 1, 1); }, {},                -1, 0);
  PHASE(0, ax, by, { RDA(ay, 1, 1, 1); },                {},                -1, 1);
  PHASE(1, ay, by, { },                                  {},                -1, 0);

  // epilogue: rows are GLU-interleaved co'; regs (x,y)/(z,w) = (a,g) channel pairs
#pragma unroll
  for (int f = 0; f < 8; ++f) {
    int cop = co0 + wm * 128 + f * 16 + ((l >> 4) << 2);
    int c = cop >> 1;
    size_t obase = ((size_t)b * (COUT2 / 2) + c) * TT;
#pragma unroll
    for (int g = 0; g < 4; ++g) {
      int t = t0 + wn * 64 + g * 16 + (l & 15);
      f32x4 v = acc[f][g];
      out[obase + t]      = v.x / (1.f + __expf(-v.y));
      out[obase + TT + t] = v.z / (1.f + __expf(-v.w));
    }
  }
}

extern "C" void kernel_launch(void* const* d_in, const int* in_sizes, int n_in,
                              void* d_out, int out_size, void* d_ws, size_t ws_size,
                              hipStream_t stream) {
  const float* x      = (const float*)d_in[0];
  const float* c_trg  = (const float*)d_in[2];
  const float* w_s    = (const float*)d_in[3];
  const float* b_s    = (const float*)d_in[4];
  const float* w_b    = (const float*)d_in[5];
  const float* b_b    = (const float*)d_in[6];
  const float* weight = (const float*)d_in[7];
  float* out = (float*)d_out;

  char* ws = (char*)d_ws;
  float*   s     = (float*)ws;                           // 32 KB
  float*   beta  = (float*)(ws + 32768);                 // 32 KB
  ushortT* xT    = (ushortT*)(ws + 65536);               // 33,587,200 B
  ushortT* wnorm = (ushortT*)(ws + 65536 + 33587200);    // 50,331,648 B

  (void)hipFuncSetAttribute((const void*)conv_gemm8,
                            hipFuncAttributeMaxDynamicSharedMemorySize, 131072);

  style_kernel<<<32, 256, 0, stream>>>(c_trg, w_s, b_s, w_b, b_b, s, beta, xT);
  xpose_kernel<<<512, 256, 0, stream>>>(x, xT);
  modw_kernel<<<1024, 256, 0, stream>>>(weight, s, beta, wnorm);
  conv_gemm8<<<512, 512, 131072, stream>>>(wnorm, xT, out);
}